// Round 3
// baseline (332.324 us; speedup 1.0000x reference)
//
#include <hip/hip_runtime.h>

#define T_STEPS 301
#define IN_DIM  40

typedef __attribute__((ext_vector_type(8))) short bf16x8;
typedef __attribute__((ext_vector_type(4))) float f32x4;
typedef unsigned short ushort_t;
typedef unsigned int uint_t;

__device__ __forceinline__ float sigm(float x) {
  return __builtin_amdgcn_rcpf(1.0f + __expf(-x));
}
__device__ __forceinline__ float tanh_fast(float x) {
  return 1.0f - 2.0f * __builtin_amdgcn_rcpf(__expf(2.0f * x) + 1.0f);
}
__device__ __forceinline__ ushort_t bf16_rn(float f) {
  uint_t u = __float_as_uint(f);
  uint_t r = u + 0x7FFFu + ((u >> 16) & 1u);
  return (ushort_t)(r >> 16);
}
__device__ __forceinline__ void split1(float f, ushort_t& hi, ushort_t& lo) {
  hi = bf16_rn(f);
  float fhi = __uint_as_float((uint_t)hi << 16);
  lo = bf16_rn(f - fhi);
}
__device__ __forceinline__ void split8(const float* v, bf16x8& hi, bf16x8& lo) {
#pragma unroll
  for (int e = 0; e < 8; ++e) {
    ushort_t h, l;
    split1(v[e], h, l);
    hi[e] = (short)h;
    lo[e] = (short)l;
  }
}

// 512 threads = 8 waves. Waves 0-3 (R): recurrence + activations for hidden strip
// n in [16w,16w+16), all 4 gates (activation fully in-register). Waves 4-7 (P):
// input projection xw[t+1] = x@w_ih^T + bias, handed off via LDS in D-frag layout.
__global__ __launch_bounds__(512, 2)
void lstm_pc(const float* __restrict__ x, const float* __restrict__ w_ih,
             const float* __restrict__ w_hh, const float* __restrict__ b_ih,
             const float* __restrict__ b_hh, const float* __restrict__ w_clf,
             const float* __restrict__ b_clf, float* __restrict__ out) {
  __shared__ ushort_t hbuf[2][2][16][64];      // h exchange: [buf][hi/lo][b][chunks], 8 KB
  __shared__ float xwbuf[2][4][4][64][4];      // xw handoff: [buf][gate][strip][lane][reg], 32 KB
  __shared__ float red[64][17];                // epilogue reduce

  const int tid = threadIdx.x;
  const int l   = tid & 63;
  const int wv  = tid >> 6;       // 0..7
  const bool isR = (wv < 4);
  const int w   = wv & 3;         // hidden strip id
  const int col = l & 15;         // A-row (batch) / B,D-col (n')
  const int g16 = l >> 4;         // k-group / D-row group
  const int n   = w * 16 + col;   // hidden index
  const int b0  = blockIdx.x * 16;

  // ---- weight B-frags in registers: R gets w_hh, P gets w_ih ----
  bf16x8 wbh[4][2], wbl[4][2];
  if (isR) {
#pragma unroll
    for (int c = 0; c < 4; ++c) {
      const float* wr = w_hh + (size_t)(c * 64 + n) * 64;
#pragma unroll
      for (int kc = 0; kc < 2; ++kc) {
        float v[8];
        *(float4*)&v[0] = *(const float4*)(wr + kc * 32 + g16 * 8);
        *(float4*)&v[4] = *(const float4*)(wr + kc * 32 + g16 * 8 + 4);
        split8(v, wbh[c][kc], wbl[c][kc]);
      }
    }
  } else {
#pragma unroll
    for (int c = 0; c < 4; ++c) {
      const float* wr = w_ih + (size_t)(c * 64 + n) * IN_DIM;
      {
        float v[8];
        *(float4*)&v[0] = *(const float4*)(wr + g16 * 8);
        *(float4*)&v[4] = *(const float4*)(wr + g16 * 8 + 4);
        split8(v, wbh[c][0], wbl[c][0]);
      }
      {
        float v[8] = {0, 0, 0, 0, 0, 0, 0, 0};
        if (g16 == 0) {
          *(float4*)&v[0] = *(const float4*)(wr + 32);
          *(float4*)&v[4] = *(const float4*)(wr + 36);
        }
        split8(v, wbh[c][1], wbl[c][1]);
      }
    }
  }

  float biasv[4] = {0.f, 0.f, 0.f, 0.f};
  if (!isR) {
#pragma unroll
    for (int c = 0; c < 4; ++c) biasv[c] = b_ih[c * 64 + n] + b_hh[c * 64 + n];
  }

  // zero hbuf[0] (t=0 reads h=0)
  {
    uint_t* hz = (uint_t*)&hbuf[0][0][0][0];
    for (int i = tid; i < 1024; i += 512) hz[i] = 0;
  }

  float cc[4]   = {0.f, 0.f, 0.f, 0.f};
  float aclf[4] = {0.f, 0.f, 0.f, 0.f};
  float wc_cur  = 0.f;
  if (isR) wc_cur = w_clf[n];   // t=0 prefetch

  // P: x regs for the step it will compute next (s = t+1)
  float4 xa0, xa1, xb0 = make_float4(0, 0, 0, 0), xb1 = make_float4(0, 0, 0, 0);
  const float* xp = nullptr;
  if (!isR) {
    xp  = x + (size_t)(b0 + col) * T_STEPS * IN_DIM + g16 * 8;
    xa0 = *(const float4*)xp;
    xa1 = *(const float4*)(xp + 4);
    if (g16 == 0) {
      xb0 = *(const float4*)(xp + 32);
      xb1 = *(const float4*)(xp + 36);
    }
  }

  for (int t = -1; t < T_STEPS; ++t) {
    if (!isR) {
      const int s = t + 1;                 // step whose xw we produce
      if (s < T_STEPS) {
        bf16x8 xh[2], xl[2];
        {
          float v[8];
          *(float4*)&v[0] = xa0; *(float4*)&v[4] = xa1;
          split8(v, xh[0], xl[0]);
        }
        {
          float v[8];
          *(float4*)&v[0] = xb0; *(float4*)&v[4] = xb1;
          split8(v, xh[1], xl[1]);
        }
        if (s + 1 < T_STEPS) {             // prefetch x for s+1
          xp += IN_DIM;
          xa0 = *(const float4*)xp;
          xa1 = *(const float4*)(xp + 4);
          if (g16 == 0) {
            xb0 = *(const float4*)(xp + 32);
            xb1 = *(const float4*)(xp + 36);
          }
        }
        f32x4 acc[4];
#pragma unroll
        for (int c = 0; c < 4; ++c) acc[c] = (f32x4){biasv[c], biasv[c], biasv[c], biasv[c]};
#pragma unroll
        for (int c = 0; c < 4; ++c) {
#pragma unroll
          for (int kc = 0; kc < 2; ++kc) {
            acc[c] = __builtin_amdgcn_mfma_f32_16x16x32_bf16(xh[kc], wbh[c][kc], acc[c], 0, 0, 0);
            acc[c] = __builtin_amdgcn_mfma_f32_16x16x32_bf16(xl[kc], wbh[c][kc], acc[c], 0, 0, 0);
            acc[c] = __builtin_amdgcn_mfma_f32_16x16x32_bf16(xh[kc], wbl[c][kc], acc[c], 0, 0, 0);
          }
        }
        const int sb = s & 1;
#pragma unroll
        for (int c = 0; c < 4; ++c)
          *(f32x4*)&xwbuf[sb][c][w][l][0] = acc[c];
      }
    } else if (t >= 0) {
      const int br = t & 1, bw = br ^ 1;

      bf16x8 ah[2], al[2];
#pragma unroll
      for (int kc = 0; kc < 2; ++kc) {
        const int cj = (kc * 4 + g16) ^ (col & 7);
        ah[kc] = *(const bf16x8*)&hbuf[br][0][col][cj * 8];
        al[kc] = *(const bf16x8*)&hbuf[br][1][col][cj * 8];
      }
      f32x4 acc[4];
#pragma unroll
      for (int c = 0; c < 4; ++c)
        acc[c] = *(const f32x4*)&xwbuf[br][c][w][l][0];
#pragma unroll
      for (int c = 0; c < 4; ++c) {
#pragma unroll
        for (int kc = 0; kc < 2; ++kc) {
          acc[c] = __builtin_amdgcn_mfma_f32_16x16x32_bf16(ah[kc], wbh[c][kc], acc[c], 0, 0, 0);
          acc[c] = __builtin_amdgcn_mfma_f32_16x16x32_bf16(al[kc], wbh[c][kc], acc[c], 0, 0, 0);
          acc[c] = __builtin_amdgcn_mfma_f32_16x16x32_bf16(ah[kc], wbl[c][kc], acc[c], 0, 0, 0);
        }
      }
      const float wcn = w_clf[(t + 1 < T_STEPS ? t + 1 : t) * 64 + n];  // prefetch

#pragma unroll
      for (int r = 0; r < 4; ++r) {
        const float zi = acc[0][r], zf = acc[1][r], zg = acc[2][r], zo = acc[3][r];
        cc[r] = sigm(zf) * cc[r] + sigm(zi) * tanh_fast(zg);
        const float h = sigm(zo) * tanh_fast(cc[r]);
        aclf[r] += h * wc_cur;
        const int b = g16 * 4 + r;
        ushort_t hh, hl;
        split1(h, hh, hl);
        const int idx = ((n >> 3) ^ (b & 7)) * 8 + (n & 7);
        hbuf[bw][0][b][idx] = hh;
        hbuf[bw][1][b][idx] = hl;
      }
      wc_cur = wcn;
    }
    __syncthreads();
  }

  // ---- epilogue: reduce classifier partials over hidden dim ----
  if (isR) {
#pragma unroll
    for (int r = 0; r < 4; ++r) red[n][g16 * 4 + r] = aclf[r];
  }
  __syncthreads();
  if (tid < 16) {
    float s = b_clf[0];
#pragma unroll 8
    for (int j = 0; j < 64; ++j) s += red[j][tid];
    out[blockIdx.x * 16 + tid] = s;
  }
}

extern "C" void kernel_launch(void* const* d_in, const int* in_sizes, int n_in,
                              void* d_out, int out_size, void* d_ws, size_t ws_size,
                              hipStream_t stream) {
  const float* x     = (const float*)d_in[0];
  const float* w_ih  = (const float*)d_in[1];
  const float* w_hh  = (const float*)d_in[2];
  const float* b_ih  = (const float*)d_in[3];
  const float* b_hh  = (const float*)d_in[4];
  const float* w_clf = (const float*)d_in[5];
  const float* b_clf = (const float*)d_in[6];
  float* out = (float*)d_out;

  lstm_pc<<<256, 512, 0, stream>>>(x, w_ih, w_hh, b_ih, b_hh, w_clf, b_clf, out);
}